// Round 1
// baseline (1199.933 us; speedup 1.0000x reference)
//
#include <hip/hip_runtime.h>
#include <hip/hip_bf16.h>

// RT-DETR multi-scale deformable attention, MI355X (gfx950).
// Round 1: correctness-first f32 pipeline; v stored bf16 (fits L3, halves gather BW).
// Stages: [A] value GEMM -> v(bf16)  [B] query -> sampling locs + softmax attn
//         [C] bilinear gather + weighted accumulate  [D] output GEMM.

#define BS 8
#define LQ 300
#define LEN_V 34000
#define ED 256
#define NH 8
#define NL 4
#define NP 4

// ---------------- Kernel A: v = value @ Wv^T + bv, store bf16 -----------------
// One block = 16 rows of value. 256 threads, thread t owns output column t.
__global__ __launch_bounds__(256) void k_value_proj(
    const float* __restrict__ value, const float* __restrict__ Wv,
    const float* __restrict__ bv, __hip_bfloat16* __restrict__ v) {
  __shared__ __align__(16) float As[16][ED];
  const int t = threadIdx.x;
  const size_t row0 = (size_t)blockIdx.x * 16;

  // stage 16 rows (16 KiB) into LDS with float4 loads
  const float4* src = (const float4*)(value + row0 * ED);
  float4* dst = (float4*)&As[0][0];
#pragma unroll
  for (int i = 0; i < 4; ++i) dst[t + i * 256] = src[t + i * 256];
  __syncthreads();

  float acc[16];
  const float bias = bv[t];
#pragma unroll
  for (int r = 0; r < 16; ++r) acc[r] = bias;

  const float4* w4 = (const float4*)(Wv + (size_t)t * ED);
  for (int k4 = 0; k4 < 64; ++k4) {
    float4 w = w4[k4];
#pragma unroll
    for (int r = 0; r < 16; ++r) {
      float4 a = ((const float4*)As[r])[k4];  // wave-uniform addr -> LDS broadcast
      acc[r] = fmaf(a.x, w.x, fmaf(a.y, w.y, fmaf(a.z, w.z, fmaf(a.w, w.w, acc[r]))));
    }
  }

  __hip_bfloat16* outp = v + row0 * ED + t;
#pragma unroll
  for (int r = 0; r < 16; ++r) outp[(size_t)r * ED] = __float2bfloat16(acc[r]);
}

// ---------------- Kernel B: sampling locations + softmax attn weights ---------
// One block per (b,q). t<256 -> loc col t (order h,l,p,c); t<128 -> attn logit.
__global__ __launch_bounds__(256) void k_qproj(
    const float* __restrict__ query, const float* __restrict__ refp,
    const float* __restrict__ Woff, const float* __restrict__ boff,
    const float* __restrict__ Wattn, const float* __restrict__ battn,
    float* __restrict__ loc, float* __restrict__ aw) {
  __shared__ __align__(16) float qs[ED];
  __shared__ float lg[NH * NL * NP];
  const int t = threadIdx.x;
  const int bq = blockIdx.x;

  qs[t] = query[(size_t)bq * ED + t];
  __syncthreads();

  const float4* q4 = (const float4*)qs;
  {
    float acc = boff[t];
    const float4* w4 = (const float4*)(Woff + (size_t)t * ED);
    for (int k = 0; k < 64; ++k) {
      float4 w = w4[k];
      float4 q = q4[k];
      acc = fmaf(q.x, w.x, fmaf(q.y, w.y, fmaf(q.z, w.z, fmaf(q.w, w.w, acc))));
    }
    const int c = t & 1;
    const int l = (t >> 3) & 3;
    const float norm = (float)(160 >> l);  // levels 160,80,40,20 (square)
    const float r = refp[((size_t)bq * NL + l) * 2 + c];
    loc[(size_t)bq * 256 + t] = r + acc / norm;
  }
  if (t < 128) {
    float acc = battn[t];
    const float4* w4 = (const float4*)(Wattn + (size_t)t * ED);
    for (int k = 0; k < 64; ++k) {
      float4 w = w4[k];
      float4 q = q4[k];
      acc = fmaf(q.x, w.x, fmaf(q.y, w.y, fmaf(q.z, w.z, fmaf(q.w, w.w, acc))));
    }
    lg[t] = acc;
  }
  __syncthreads();
  if (t < NH) {  // per-head softmax over nl*np = 16
    float m = -1e30f;
#pragma unroll
    for (int i = 0; i < 16; ++i) m = fmaxf(m, lg[t * 16 + i]);
    float e[16];
    float s = 0.f;
#pragma unroll
    for (int i = 0; i < 16; ++i) {
      e[i] = expf(lg[t * 16 + i] - m);
      s += e[i];
    }
    const float inv = 1.f / s;
#pragma unroll
    for (int i = 0; i < 16; ++i) aw[(size_t)bq * 128 + t * 16 + i] = e[i] * inv;
  }
}

// ---------------- Kernel C: bilinear sampling + weighted accumulate -----------
__device__ __forceinline__ float sample_one(const __hip_bfloat16* __restrict__ vb,
                                            int st, int W, int H, int xi, int yi,
                                            int t) {
  const bool valid = (xi >= 0) & (xi < W) & (yi >= 0) & (yi < H);
  const int xc = min(max(xi, 0), W - 1);
  const int yc = min(max(yi, 0), H - 1);
  const float g = __bfloat162float(vb[((size_t)(st + yc * W + xc)) * ED + t]);
  return valid ? g : 0.f;
}

__global__ __launch_bounds__(256) void k_sample(
    const __hip_bfloat16* __restrict__ v, const float* __restrict__ loc,
    const float* __restrict__ aw, float* __restrict__ inner) {
  const int t = threadIdx.x;  // t = h*32 + d
  const int bq = blockIdx.x;
  const int b = bq / LQ;
  const int h = t >> 5;
  const __hip_bfloat16* vb = v + (size_t)b * LEN_V * ED;
  const float* locq = loc + (size_t)bq * 256;
  const float* awq = aw + (size_t)bq * 128;

  float acc = 0.f;
#pragma unroll
  for (int l = 0; l < NL; ++l) {
    const int W = 160 >> l;
    const int H = W;
    const int st = (l == 0) ? 0 : (l == 1) ? 25600 : (l == 2) ? 32000 : 33600;
#pragma unroll
    for (int p = 0; p < NP; ++p) {
      const int base = ((h * NL + l) * NP + p) * 2;
      const float lx = locq[base];
      const float ly = locq[base + 1];
      const float w = awq[h * 16 + l * 4 + p];
      const float x = lx * (float)W - 0.5f;
      const float y = ly * (float)H - 0.5f;
      const float x0f = floorf(x);
      const float y0f = floorf(y);
      const float wx = x - x0f;
      const float wy = y - y0f;
      const int x0 = (int)x0f;
      const int y0 = (int)y0f;
      const float g00 = sample_one(vb, st, W, H, x0, y0, t);
      const float g01 = sample_one(vb, st, W, H, x0 + 1, y0, t);
      const float g10 = sample_one(vb, st, W, H, x0, y0 + 1, t);
      const float g11 = sample_one(vb, st, W, H, x0 + 1, y0 + 1, t);
      const float vxy = (g00 * (1.f - wx) + g01 * wx) * (1.f - wy) +
                        (g10 * (1.f - wx) + g11 * wx) * wy;
      acc = fmaf(w, vxy, acc);
    }
  }
  inner[(size_t)bq * ED + t] = acc;
}

// ---------------- Kernel D: out = inner @ Wout^T + bout -----------------------
__global__ __launch_bounds__(256) void k_outproj(
    const float* __restrict__ inner, const float* __restrict__ Wout,
    const float* __restrict__ bout, float* __restrict__ out) {
  __shared__ __align__(16) float s[ED];
  const int t = threadIdx.x;
  const int bq = blockIdx.x;
  s[t] = inner[(size_t)bq * ED + t];
  __syncthreads();
  float acc = bout[t];
  const float4* w4 = (const float4*)(Wout + (size_t)t * ED);
  const float4* q4 = (const float4*)s;
  for (int k = 0; k < 64; ++k) {
    float4 w = w4[k];
    float4 q = q4[k];
    acc = fmaf(q.x, w.x, fmaf(q.y, w.y, fmaf(q.z, w.z, fmaf(q.w, w.w, acc))));
  }
  out[(size_t)bq * ED + t] = acc;
}

extern "C" void kernel_launch(void* const* d_in, const int* in_sizes, int n_in,
                              void* d_out, int out_size, void* d_ws, size_t ws_size,
                              hipStream_t stream) {
  const float* query = (const float*)d_in[0];
  const float* refp  = (const float*)d_in[1];
  const float* value = (const float*)d_in[2];
  const float* Wv    = (const float*)d_in[3];
  const float* bv    = (const float*)d_in[4];
  const float* Woff  = (const float*)d_in[5];
  const float* boff  = (const float*)d_in[6];
  const float* Wattn = (const float*)d_in[7];
  const float* battn = (const float*)d_in[8];
  const float* Wout  = (const float*)d_in[9];
  const float* bout  = (const float*)d_in[10];
  float* out = (float*)d_out;

  char* ws = (char*)d_ws;
  // v(bf16): 272000*256*2 = 139,264,000 B
  __hip_bfloat16* v = (__hip_bfloat16*)ws;
  size_t off = ((size_t)BS * LEN_V * ED * 2 + 255) & ~(size_t)255;
  float* loc = (float*)(ws + off);            // 2400*256*4 = 2.46 MB
  off += (size_t)BS * LQ * 256 * 4;
  float* aw = (float*)(ws + off);             // 2400*128*4 = 1.23 MB
  off += (size_t)BS * LQ * 128 * 4;
  float* inner = (float*)(ws + off);          // 2400*256*4 = 2.46 MB

  k_value_proj<<<BS * LEN_V / 16, 256, 0, stream>>>(value, Wv, bv, v);
  k_qproj<<<BS * LQ, 256, 0, stream>>>(query, refp, Woff, boff, Wattn, battn, loc, aw);
  k_sample<<<BS * LQ, 256, 0, stream>>>(v, loc, aw, inner);
  k_outproj<<<BS * LQ, 256, 0, stream>>>(inner, Wout, bout, out);
}

// Round 3
// 656.194 us; speedup vs baseline: 1.8286x; 1.8286x over previous
//
#include <hip/hip_runtime.h>
#include <hip/hip_bf16.h>

// RT-DETR multi-scale deformable attention, MI355X (gfx950).
// Round 3: fix R2 staging bug (each thread now stages its full 16 f32 -> 16 bf16).
// Stages: [A] value GEMM (MFMA bf16 16x16x32) -> v(bf16)  [B] query -> locs + softmax
//         [C] bilinear gather + weighted accumulate  [D] output GEMM.

#define BS 8
#define LQ 300
#define LEN_V 34000
#define ED 256
#define NH 8
#define NL 4
#define NP 4

#define BM 128
#define BN 128
#define BK 32
#define LDT 40  // padded LDS row stride (bf16): 80B = 20 banks -> max 2-way (free)

typedef short short8 __attribute__((ext_vector_type(8)));
typedef float f32x4 __attribute__((ext_vector_type(4)));

__device__ __forceinline__ void cvt8_store(__hip_bfloat16* dst, float4 a, float4 b) {
  union { short8 v; __hip_bfloat16 h[8]; } u;
  u.h[0] = __float2bfloat16(a.x); u.h[1] = __float2bfloat16(a.y);
  u.h[2] = __float2bfloat16(a.z); u.h[3] = __float2bfloat16(a.w);
  u.h[4] = __float2bfloat16(b.x); u.h[5] = __float2bfloat16(b.y);
  u.h[6] = __float2bfloat16(b.z); u.h[7] = __float2bfloat16(b.w);
  *(short8*)dst = u.v;
}

// ---------------- Kernel A: v = value @ Wv^T + bv (bf16 MFMA) -----------------
// Block: 256 thr (4 waves), tile 128x128. Wave w: rows (w&1)*64, cols (w>>1)*64.
// Staging: thread t owns row sr=t>>1, f32 cols [sk, sk+16), sk=(t&1)*16.
__global__ __launch_bounds__(256) void k_value_proj(
    const float* __restrict__ value, const float* __restrict__ Wv,
    const float* __restrict__ bv, __hip_bfloat16* __restrict__ v) {
  __shared__ __align__(16) __hip_bfloat16 As[BM][LDT];
  __shared__ __align__(16) __hip_bfloat16 Bs[BM][LDT];

  const int t = threadIdx.x;
  const int bm = blockIdx.x >> 1;
  const int n0 = (blockIdx.x & 1) * BN;
  const size_t row0 = (size_t)bm * BM;

  const int sr = t >> 1;          // staging row 0..127
  const int sk = (t & 1) * 16;    // staging k offset (f32 elems)

  const int wave = t >> 6;
  const int lane = t & 63;
  const int mw = (wave & 1) * 64;
  const int nw = (wave >> 1) * 64;
  const int fr = lane & 15;        // fragment row/col index
  const int fk = (lane >> 4) * 8;  // fragment k offset

  f32x4 acc[4][4];
#pragma unroll
  for (int i = 0; i < 4; ++i)
#pragma unroll
    for (int j = 0; j < 4; ++j) acc[i][j] = (f32x4){0.f, 0.f, 0.f, 0.f};

  const float* gA = value + (row0 + sr) * (size_t)ED + sk;
  const float* gB = Wv + (size_t)(n0 + sr) * ED + sk;

  for (int kk = 0; kk < ED; kk += BK) {
    // stage A,B tiles: each thread 16 f32 -> 16 bf16 (2x ds_write_b128 each)
    float4 a0 = ((const float4*)(gA + kk))[0];
    float4 a1 = ((const float4*)(gA + kk))[1];
    float4 a2 = ((const float4*)(gA + kk))[2];
    float4 a3 = ((const float4*)(gA + kk))[3];
    float4 b0 = ((const float4*)(gB + kk))[0];
    float4 b1 = ((const float4*)(gB + kk))[1];
    float4 b2 = ((const float4*)(gB + kk))[2];
    float4 b3 = ((const float4*)(gB + kk))[3];
    __syncthreads();  // protect LDS reuse from previous iter
    cvt8_store(&As[sr][sk], a0, a1);
    cvt8_store(&As[sr][sk + 8], a2, a3);
    cvt8_store(&Bs[sr][sk], b0, b1);
    cvt8_store(&Bs[sr][sk + 8], b2, b3);
    __syncthreads();

    short8 afrag[4], bfrag[4];
#pragma unroll
    for (int mi = 0; mi < 4; ++mi)
      afrag[mi] = *(const short8*)&As[mw + mi * 16 + fr][fk];
#pragma unroll
    for (int ni = 0; ni < 4; ++ni)
      bfrag[ni] = *(const short8*)&Bs[nw + ni * 16 + fr][fk];

#pragma unroll
    for (int mi = 0; mi < 4; ++mi)
#pragma unroll
      for (int ni = 0; ni < 4; ++ni)
        acc[mi][ni] = __builtin_amdgcn_mfma_f32_16x16x32_bf16(
            afrag[mi], bfrag[ni], acc[mi][ni], 0, 0, 0);
  }

  // epilogue: C/D layout col=lane&15, row=(lane>>4)*4+reg
  const int rq = (lane >> 4) * 4;
#pragma unroll
  for (int ni = 0; ni < 4; ++ni) {
    const int col = n0 + nw + ni * 16 + fr;
    const float bias = bv[col];
#pragma unroll
    for (int mi = 0; mi < 4; ++mi) {
      const size_t rbase = (row0 + mw + mi * 16 + rq) * (size_t)ED + col;
#pragma unroll
      for (int r = 0; r < 4; ++r)
        v[rbase + (size_t)r * ED] = __float2bfloat16(acc[mi][ni][r] + bias);
    }
  }
}

// ---------------- Kernel B: sampling locations + softmax attn weights ---------
__global__ __launch_bounds__(256) void k_qproj(
    const float* __restrict__ query, const float* __restrict__ refp,
    const float* __restrict__ Woff, const float* __restrict__ boff,
    const float* __restrict__ Wattn, const float* __restrict__ battn,
    float* __restrict__ loc, float* __restrict__ aw) {
  __shared__ __align__(16) float qs[ED];
  __shared__ float lg[NH * NL * NP];
  const int t = threadIdx.x;
  const int bq = blockIdx.x;

  qs[t] = query[(size_t)bq * ED + t];
  __syncthreads();

  const float4* q4 = (const float4*)qs;
  {
    float acc = boff[t];
    const float4* w4 = (const float4*)(Woff + (size_t)t * ED);
    for (int k = 0; k < 64; ++k) {
      float4 w = w4[k];
      float4 q = q4[k];
      acc = fmaf(q.x, w.x, fmaf(q.y, w.y, fmaf(q.z, w.z, fmaf(q.w, w.w, acc))));
    }
    const int c = t & 1;
    const int l = (t >> 3) & 3;
    const float norm = (float)(160 >> l);
    const float r = refp[((size_t)bq * NL + l) * 2 + c];
    loc[(size_t)bq * 256 + t] = r + acc / norm;
  }
  if (t < 128) {
    float acc = battn[t];
    const float4* w4 = (const float4*)(Wattn + (size_t)t * ED);
    for (int k = 0; k < 64; ++k) {
      float4 w = w4[k];
      float4 q = q4[k];
      acc = fmaf(q.x, w.x, fmaf(q.y, w.y, fmaf(q.z, w.z, fmaf(q.w, w.w, acc))));
    }
    lg[t] = acc;
  }
  __syncthreads();
  if (t < NH) {
    float m = -1e30f;
#pragma unroll
    for (int i = 0; i < 16; ++i) m = fmaxf(m, lg[t * 16 + i]);
    float e[16];
    float s = 0.f;
#pragma unroll
    for (int i = 0; i < 16; ++i) {
      e[i] = expf(lg[t * 16 + i] - m);
      s += e[i];
    }
    const float inv = 1.f / s;
#pragma unroll
    for (int i = 0; i < 16; ++i) aw[(size_t)bq * 128 + t * 16 + i] = e[i] * inv;
  }
}

// ---------------- Kernel C: bilinear sampling + weighted accumulate -----------
__device__ __forceinline__ float sample_one(const __hip_bfloat16* __restrict__ vb,
                                            int st, int W, int H, int xi, int yi,
                                            int t) {
  const bool valid = (xi >= 0) & (xi < W) & (yi >= 0) & (yi < H);
  const int xc = min(max(xi, 0), W - 1);
  const int yc = min(max(yi, 0), H - 1);
  const float g = __bfloat162float(vb[((size_t)(st + yc * W + xc)) * ED + t]);
  return valid ? g : 0.f;
}

__global__ __launch_bounds__(256) void k_sample(
    const __hip_bfloat16* __restrict__ v, const float* __restrict__ loc,
    const float* __restrict__ aw, float* __restrict__ inner) {
  const int t = threadIdx.x;  // t = h*32 + d
  const int bq = blockIdx.x;
  const int b = bq / LQ;
  const int h = t >> 5;
  const __hip_bfloat16* vb = v + (size_t)b * LEN_V * ED;
  const float* locq = loc + (size_t)bq * 256;
  const float* awq = aw + (size_t)bq * 128;

  float acc = 0.f;
#pragma unroll
  for (int l = 0; l < NL; ++l) {
    const int W = 160 >> l;
    const int H = W;
    const int st = (l == 0) ? 0 : (l == 1) ? 25600 : (l == 2) ? 32000 : 33600;
#pragma unroll
    for (int p = 0; p < NP; ++p) {
      const int base = ((h * NL + l) * NP + p) * 2;
      const float lx = locq[base];
      const float ly = locq[base + 1];
      const float w = awq[h * 16 + l * 4 + p];
      const float x = lx * (float)W - 0.5f;
      const float y = ly * (float)H - 0.5f;
      const float x0f = floorf(x);
      const float y0f = floorf(y);
      const float wx = x - x0f;
      const float wy = y - y0f;
      const int x0 = (int)x0f;
      const int y0 = (int)y0f;
      const float g00 = sample_one(vb, st, W, H, x0, y0, t);
      const float g01 = sample_one(vb, st, W, H, x0 + 1, y0, t);
      const float g10 = sample_one(vb, st, W, H, x0, y0 + 1, t);
      const float g11 = sample_one(vb, st, W, H, x0 + 1, y0 + 1, t);
      const float vxy = (g00 * (1.f - wx) + g01 * wx) * (1.f - wy) +
                        (g10 * (1.f - wx) + g11 * wx) * wy;
      acc = fmaf(w, vxy, acc);
    }
  }
  inner[(size_t)bq * ED + t] = acc;
}

// ---------------- Kernel D: out = inner @ Wout^T + bout -----------------------
__global__ __launch_bounds__(256) void k_outproj(
    const float* __restrict__ inner, const float* __restrict__ Wout,
    const float* __restrict__ bout, float* __restrict__ out) {
  __shared__ __align__(16) float s[ED];
  const int t = threadIdx.x;
  const int bq = blockIdx.x;
  s[t] = inner[(size_t)bq * ED + t];
  __syncthreads();
  float acc = bout[t];
  const float4* w4 = (const float4*)(Wout + (size_t)t * ED);
  const float4* q4 = (const float4*)s;
  for (int k = 0; k < 64; ++k) {
    float4 w = w4[k];
    float4 q = q4[k];
    acc = fmaf(q.x, w.x, fmaf(q.y, w.y, fmaf(q.z, w.z, fmaf(q.w, w.w, acc))));
  }
  out[(size_t)bq * ED + t] = acc;
}

extern "C" void kernel_launch(void* const* d_in, const int* in_sizes, int n_in,
                              void* d_out, int out_size, void* d_ws, size_t ws_size,
                              hipStream_t stream) {
  const float* query = (const float*)d_in[0];
  const float* refp  = (const float*)d_in[1];
  const float* value = (const float*)d_in[2];
  const float* Wv    = (const float*)d_in[3];
  const float* bv    = (const float*)d_in[4];
  const float* Woff  = (const float*)d_in[5];
  const float* boff  = (const float*)d_in[6];
  const float* Wattn = (const float*)d_in[7];
  const float* battn = (const float*)d_in[8];
  const float* Wout  = (const float*)d_in[9];
  const float* bout  = (const float*)d_in[10];
  float* out = (float*)d_out;

  char* ws = (char*)d_ws;
  __hip_bfloat16* v = (__hip_bfloat16*)ws;  // 272000*256*2 B
  size_t off = ((size_t)BS * LEN_V * ED * 2 + 255) & ~(size_t)255;
  float* loc = (float*)(ws + off);
  off += (size_t)BS * LQ * 256 * 4;
  float* aw = (float*)(ws + off);
  off += (size_t)BS * LQ * 128 * 4;
  float* inner = (float*)(ws + off);

  // M=272000 -> 2125 row-blocks of 128; N=256 -> 2 col-blocks
  k_value_proj<<<2125 * 2, 256, 0, stream>>>(value, Wv, bv, v);
  k_qproj<<<BS * LQ, 256, 0, stream>>>(query, refp, Woff, boff, Wattn, battn, loc, aw);
  k_sample<<<BS * LQ, 256, 0, stream>>>(v, loc, aw, inner);
  k_outproj<<<BS * LQ, 256, 0, stream>>>(inner, Wout, bout, out);
}

// Round 4
// 598.835 us; speedup vs baseline: 2.0038x; 1.0958x over previous
//
#include <hip/hip_runtime.h>
#include <hip/hip_bf16.h>

// RT-DETR multi-scale deformable attention, MI355X (gfx950).
// Round 4: all three projections via one templated MFMA GEMM (coalesced staging,
// M-masked); qproj weights concatenated (N=384); sample kernel point-parallel
// (512 thr) with LDS reduction; loc/softmax computed in-place in offs buffer.

#define BS 8
#define LQ 300
#define LEN_V 34000
#define ED 256
#define NH 8
#define NL 4
#define NP 4

#define LDT 40  // padded LDS row stride (bf16): 80B = 20 banks -> max 2-way (free)

typedef short short8 __attribute__((ext_vector_type(8)));
typedef float f32x4 __attribute__((ext_vector_type(4)));

__device__ __forceinline__ void cvt8_store(__hip_bfloat16* dst, float4 a, float4 b) {
  union { short8 v; __hip_bfloat16 h[8]; } u;
  u.h[0] = __float2bfloat16(a.x); u.h[1] = __float2bfloat16(a.y);
  u.h[2] = __float2bfloat16(a.z); u.h[3] = __float2bfloat16(a.w);
  u.h[4] = __float2bfloat16(b.x); u.h[5] = __float2bfloat16(b.y);
  u.h[6] = __float2bfloat16(b.z); u.h[7] = __float2bfloat16(b.w);
  *(short8*)dst = u.v;
}

__device__ __forceinline__ void store_elem(float* p, float x) { *p = x; }
__device__ __forceinline__ void store_elem(__hip_bfloat16* p, float x) {
  *p = __float2bfloat16(x);
}

// ---------------- Generic MFMA GEMM: C[M x ldc] = A[M x 256] @ B[N x 256]^T + bias
// Block 256 thr (4 waves), tile 128x128, BK=32, K=256. grid=(ceil(M/128), N/128).
// Staging: thread t owns rows sr=t>>2 (+64), f32 cols [(t&3)*8, +8) -> coalesced
// 32B-per-4-lane windows. A rows clamped to M-1; stores guarded by row<M.
template <typename OutT>
__global__ __launch_bounds__(256) void k_gemm(
    const float* __restrict__ A, const float* __restrict__ B,
    const float* __restrict__ bias, OutT* __restrict__ C, int M, int ldc) {
  __shared__ __align__(16) __hip_bfloat16 As[128][LDT];
  __shared__ __align__(16) __hip_bfloat16 Bs[128][LDT];

  const int t = threadIdx.x;
  const size_t row0 = (size_t)blockIdx.x * 128;
  const int n0 = blockIdx.y * 128;

  const int sr = t >> 2;          // staging row 0..63 (+64 for slab 1)
  const int sc = (t & 3) * 8;     // staging f32 col offset

  const int wave = t >> 6;
  const int lane = t & 63;
  const int mw = (wave & 1) * 64;
  const int nw = (wave >> 1) * 64;
  const int fr = lane & 15;
  const int fk = (lane >> 4) * 8;

  f32x4 acc[4][4];
#pragma unroll
  for (int i = 0; i < 4; ++i)
#pragma unroll
    for (int j = 0; j < 4; ++j) acc[i][j] = (f32x4){0.f, 0.f, 0.f, 0.f};

  const size_t rA0 = min(row0 + sr, (size_t)(M - 1));
  const size_t rA1 = min(row0 + sr + 64, (size_t)(M - 1));
  const float* gA0 = A + rA0 * ED + sc;
  const float* gA1 = A + rA1 * ED + sc;
  const float* gB0 = B + (size_t)(n0 + sr) * ED + sc;
  const float* gB1 = B + (size_t)(n0 + sr + 64) * ED + sc;

  for (int kk = 0; kk < ED; kk += 32) {
    float4 a00 = ((const float4*)(gA0 + kk))[0];
    float4 a01 = ((const float4*)(gA0 + kk))[1];
    float4 a10 = ((const float4*)(gA1 + kk))[0];
    float4 a11 = ((const float4*)(gA1 + kk))[1];
    float4 b00 = ((const float4*)(gB0 + kk))[0];
    float4 b01 = ((const float4*)(gB0 + kk))[1];
    float4 b10 = ((const float4*)(gB1 + kk))[0];
    float4 b11 = ((const float4*)(gB1 + kk))[1];
    __syncthreads();  // protect LDS reuse from previous iter
    cvt8_store(&As[sr][sc], a00, a01);
    cvt8_store(&As[sr + 64][sc], a10, a11);
    cvt8_store(&Bs[sr][sc], b00, b01);
    cvt8_store(&Bs[sr + 64][sc], b10, b11);
    __syncthreads();

    short8 afrag[4], bfrag[4];
#pragma unroll
    for (int mi = 0; mi < 4; ++mi)
      afrag[mi] = *(const short8*)&As[mw + mi * 16 + fr][fk];
#pragma unroll
    for (int ni = 0; ni < 4; ++ni)
      bfrag[ni] = *(const short8*)&Bs[nw + ni * 16 + fr][fk];

#pragma unroll
    for (int mi = 0; mi < 4; ++mi)
#pragma unroll
      for (int ni = 0; ni < 4; ++ni)
        acc[mi][ni] = __builtin_amdgcn_mfma_f32_16x16x32_bf16(
            afrag[mi], bfrag[ni], acc[mi][ni], 0, 0, 0);
  }

  // epilogue: C/D layout col=lane&15, row=(lane>>4)*4+reg
  const int rq = (lane >> 4) * 4;
#pragma unroll
  for (int ni = 0; ni < 4; ++ni) {
    const int col = n0 + nw + ni * 16 + fr;
    const float bias_v = bias[col];
#pragma unroll
    for (int mi = 0; mi < 4; ++mi) {
      const size_t rbase = row0 + mw + mi * 16 + rq;
#pragma unroll
      for (int r = 0; r < 4; ++r) {
        const size_t row = rbase + r;
        if (row < (size_t)M)
          store_elem(&C[row * (size_t)ldc + col], acc[mi][ni][r] + bias_v);
      }
    }
  }
}

// ---------------- Concat Woff(256x256) + Wattn(128x256) -> Wcat(384x256) ------
__global__ __launch_bounds__(256) void k_concat(
    const float* __restrict__ Woff, const float* __restrict__ boff,
    const float* __restrict__ Wattn, const float* __restrict__ battn,
    float* __restrict__ Wcat, float* __restrict__ bcat) {
  const int row = blockIdx.x;  // 0..383
  const int t = threadIdx.x;
  const float* src = (row < 256) ? (Woff + (size_t)row * ED)
                                 : (Wattn + (size_t)(row - 256) * ED);
  Wcat[(size_t)row * ED + t] = src[t];
  if (t == 0) bcat[row] = (row < 256) ? boff[row] : battn[row - 256];
}

// ---------------- Post: loc + softmax, in-place in offs[2400 x 384] -----------
// cols 0..255: offsets -> loc;  cols 256..383: logits -> softmaxed attn weights.
__global__ __launch_bounds__(256) void k_post(
    const float* __restrict__ refp, float* __restrict__ offs) {
  __shared__ float lg[128];
  const int t = threadIdx.x;
  const int bq = blockIdx.x;
  float* row = offs + (size_t)bq * 384;
  if (t < 128) lg[t] = row[256 + t];
  const float o = row[t];
  const int c = t & 1;
  const int l = (t >> 3) & 3;
  const float norm = (float)(160 >> l);
  const float r = refp[((size_t)bq * NL + l) * 2 + c];
  __syncthreads();
  row[t] = r + o / norm;
  if (t < NH) {
    float m = -1e30f;
#pragma unroll
    for (int i = 0; i < 16; ++i) m = fmaxf(m, lg[t * 16 + i]);
    float e[16];
    float s = 0.f;
#pragma unroll
    for (int i = 0; i < 16; ++i) {
      e[i] = expf(lg[t * 16 + i] - m);
      s += e[i];
    }
    const float inv = 1.f / s;
#pragma unroll
    for (int i = 0; i < 16; ++i) row[256 + t * 16 + i] = e[i] * inv;
  }
}

// ---------------- Sample: point-parallel bilinear gather + LDS reduce ---------
// Block 512 thr = 16 points (pi) x 32 channels (d); loop h=0..7.
__device__ __forceinline__ float sample_one(const __hip_bfloat16* __restrict__ vb,
                                            int st, int W, int xi, int yi, int ch) {
  const bool valid = (xi >= 0) & (xi < W) & (yi >= 0) & (yi < W);
  const int xc = min(max(xi, 0), W - 1);
  const int yc = min(max(yi, 0), W - 1);
  const float g = __bfloat162float(vb[((size_t)(st + yc * W + xc)) * ED + ch]);
  return valid ? g : 0.f;
}

__global__ __launch_bounds__(512) void k_sample(
    const __hip_bfloat16* __restrict__ v, const float* __restrict__ offs,
    float* __restrict__ inner) {
  __shared__ float part[16][256];
  __shared__ float slo[256];
  __shared__ float saw[128];
  const int t = threadIdx.x;
  const int bq = blockIdx.x;
  const int b = bq / LQ;
  const float* rowq = offs + (size_t)bq * 384;
  if (t < 256) slo[t] = rowq[t];
  else if (t < 384) saw[t - 256] = rowq[t];
  __syncthreads();

  const int pi = t >> 5;  // 0..15
  const int d = t & 31;
  const int l = pi >> 2;
  const int p = pi & 3;
  const int W = 160 >> l;
  const int st = (l == 0) ? 0 : (l == 1) ? 25600 : (l == 2) ? 32000 : 33600;
  const __hip_bfloat16* vb = v + (size_t)b * LEN_V * ED;

#pragma unroll
  for (int h = 0; h < NH; ++h) {
    const int base = ((h * NL + l) * NP + p) * 2;
    const float lx = slo[base];
    const float ly = slo[base + 1];
    const float w = saw[h * 16 + pi];
    const float x = lx * (float)W - 0.5f;
    const float y = ly * (float)W - 0.5f;
    const float x0f = floorf(x);
    const float y0f = floorf(y);
    const float wx = x - x0f;
    const float wy = y - y0f;
    const int x0 = (int)x0f;
    const int y0 = (int)y0f;
    const int ch = h * 32 + d;
    const float g00 = sample_one(vb, st, W, x0, y0, ch);
    const float g01 = sample_one(vb, st, W, x0 + 1, y0, ch);
    const float g10 = sample_one(vb, st, W, x0, y0 + 1, ch);
    const float g11 = sample_one(vb, st, W, x0 + 1, y0 + 1, ch);
    const float vxy = (g00 * (1.f - wx) + g01 * wx) * (1.f - wy) +
                      (g10 * (1.f - wx) + g11 * wx) * wy;
    part[pi][ch] = w * vxy;
  }
  __syncthreads();
  if (t < 256) {
    float s = 0.f;
#pragma unroll
    for (int q = 0; q < 16; ++q) s += part[q][t];
    inner[(size_t)bq * ED + t] = s;
  }
}

extern "C" void kernel_launch(void* const* d_in, const int* in_sizes, int n_in,
                              void* d_out, int out_size, void* d_ws, size_t ws_size,
                              hipStream_t stream) {
  const float* query = (const float*)d_in[0];
  const float* refp  = (const float*)d_in[1];
  const float* value = (const float*)d_in[2];
  const float* Wv    = (const float*)d_in[3];
  const float* bv    = (const float*)d_in[4];
  const float* Woff  = (const float*)d_in[5];
  const float* boff  = (const float*)d_in[6];
  const float* Wattn = (const float*)d_in[7];
  const float* battn = (const float*)d_in[8];
  const float* Wout  = (const float*)d_in[9];
  const float* bout  = (const float*)d_in[10];
  float* out = (float*)d_out;

  char* ws = (char*)d_ws;
  __hip_bfloat16* v = (__hip_bfloat16*)ws;        // 139,264,000 B
  size_t off = (size_t)BS * LEN_V * ED * 2;
  float* offs = (float*)(ws + off);               // 2400*384*4 = 3.69 MB
  off += (size_t)BS * LQ * 384 * 4;
  float* inner = (float*)(ws + off);              // 2400*256*4 = 2.46 MB
  off += (size_t)BS * LQ * 256 * 4;
  float* Wcat = (float*)(ws + off);               // 384*256*4
  off += (size_t)384 * ED * 4;
  float* bcat = (float*)(ws + off);               // 384*4

  const int M_Q = BS * LQ;  // 2400

  k_concat<<<384, 256, 0, stream>>>(Woff, boff, Wattn, battn, Wcat, bcat);
  // value proj: M=272000 (2125x128), N=256
  k_gemm<__hip_bfloat16><<<dim3(2125, 2), 256, 0, stream>>>(
      value, Wv, bv, v, BS * LEN_V, ED);
  // query proj (offsets + attn logits): M=2400 -> 19 blocks, N=384 -> 3
  k_gemm<float><<<dim3(19, 3), 256, 0, stream>>>(
      query, Wcat, bcat, offs, M_Q, 384);
  k_post<<<M_Q, 256, 0, stream>>>(refp, offs);
  k_sample<<<M_Q, 512, 0, stream>>>(v, offs, inner);
  // out proj: M=2400, N=256
  k_gemm<float><<<dim3(19, 2), 256, 0, stream>>>(
      inner, Wout, bout, out, M_Q, ED);
}